// Round 1
// baseline (268.415 us; speedup 1.0000x reference)
//
#include <hip/hip_runtime.h>

// CellListNL MIC neighbor predicate, N=4096, rc=5, cell = L*I (diagonal).
// Output layout (single fp32 buffer, concatenated flat in return order):
//   out[0 .. N*N)           : d2_masked[i][j]
//   out[N*N .. N*N + N*N*3) : shift[i][j][c] as float (-1/0/1), 0 if not kept
//
// Round 2: attack the write path. 268 MB of mandatory writes; harness fill
// demonstrates 6.5 TB/s on this buffer, previous kernel achieved far less.
//   - 4 pairs/thread: d2 stored as one dwordx4 (1024 B/wave/instr, contiguous)
//   - shift transposed through LDS (3x ds_write_b128 / ds_read_b128, 16B
//     contiguous = 2-way bank aliasing = free) then 3x dwordx4 stores,
//     every store instruction full-width and lane-contiguous
//   - one block per i-row (4096 blocks, 16x fewer dispatches, frac_i once)
//   - nontemporal hints: pure streaming output, don't cache in L2

constexpr int   N_ATOMS = 4096;
constexpr float RC2     = 25.0f;   // rc = 5.0
constexpr int   TPB     = 256;

typedef float v4f __attribute__((ext_vector_type(4)));

__global__ __launch_bounds__(TPB) void cellnl_kernel(
    const float* __restrict__ coord,
    const float* __restrict__ cell,
    float* __restrict__ out)
{
    __shared__ float smem[TPB * 12];   // 12 KB: one chunk's shift values

    const float L   = cell[0];          // cell = L * I
    const float inv = 1.0f / L;
    const int   i   = blockIdx.x;       // one atom row per block
    const int   t   = threadIdx.x;

    // frac_i: block-uniform -> scalar loads, computed once per block
    float fix = coord[3 * i + 0] * inv; fix -= floorf(fix);
    float fiy = coord[3 * i + 1] * inv; fiy -= floorf(fiy);
    float fiz = coord[3 * i + 2] * inv; fiz -= floorf(fiz);

    const size_t prow  = (size_t)i * N_ATOMS;
    float* const d2row = out + prow;
    float* const shrow = out + (size_t)N_ATOMS * N_ATOMS + prow * 3;

    // 4 chunks of 1024 pairs; each thread owns 4 consecutive j per chunk.
    #pragma unroll 1
    for (int c = 0; c < 4; ++c) {
        const int j0 = (c << 10) + (t << 2);

        // 4 atoms = 12 floats = 3x dwordx4 loads (48 B/lane, L2-resident)
        const v4f* cj = reinterpret_cast<const v4f*>(coord + 3 * j0);
        const v4f c0 = cj[0], c1 = cj[1], c2 = cj[2];
        const float cx[4] = {c0[0], c0[3], c1[2], c2[1]};
        const float cy[4] = {c0[1], c1[0], c1[3], c2[2]};
        const float cz[4] = {c0[2], c1[1], c2[0], c2[3]};

        v4f   d2v;
        float sv[12];
        #pragma unroll
        for (int p = 0; p < 4; ++p) {
            float fjx = cx[p] * inv; fjx -= floorf(fjx);
            float fjy = cy[p] * inv; fjy -= floorf(fjy);
            float fjz = cz[p] * inv; fjz -= floorf(fjz);
            // dfrac = frac_j - frac_i; MIC shift = -round_half_even(dfrac)
            float dx = fjx - fix, dy = fjy - fiy, dz = fjz - fiz;
            const float sx = -rintf(dx), sy = -rintf(dy), sz = -rintf(dz);
            dx = (dx + sx) * L; dy = (dy + sy) * L; dz = (dz + sz) * L;
            const float dist2 = dx * dx + dy * dy + dz * dz;
            const bool  keep  = (dist2 > 0.0f) && (dist2 < RC2);
            d2v[p]      = keep ? dist2 : 0.0f;
            sv[p*3 + 0] = keep ? sx : 0.0f;
            sv[p*3 + 1] = keep ? sy : 0.0f;
            sv[p*3 + 2] = keep ? sz : 0.0f;
        }

        // d2: 16 B/lane, wave = 1024 B contiguous, streaming
        __builtin_nontemporal_store(d2v, reinterpret_cast<v4f*>(d2row + j0));

        // shift: stage 12 floats/thread in LDS (16B-aligned b128 writes,
        // lane stride 48 B -> 2-way bank aliasing = free) ...
        #pragma unroll
        for (int k = 0; k < 3; ++k) {
            v4f w = { sv[4*k + 0], sv[4*k + 1], sv[4*k + 2], sv[4*k + 3] };
            *reinterpret_cast<v4f*>(&smem[t * 12 + k * 4]) = w;
        }
        __syncthreads();
        // ... then stream the 12 KB chunk out linearly: 3x dwordx4/thread,
        // each store instruction 1024 B/wave contiguous.
        #pragma unroll
        for (int k = 0; k < 3; ++k) {
            const v4f v = *reinterpret_cast<const v4f*>(&smem[k * 1024 + t * 4]);
            __builtin_nontemporal_store(
                v, reinterpret_cast<v4f*>(shrow + c * 3072 + k * 1024 + t * 4));
        }
        __syncthreads();   // protect smem reuse next chunk
    }
}

extern "C" void kernel_launch(void* const* d_in, const int* in_sizes, int n_in,
                              void* d_out, int out_size, void* d_ws, size_t ws_size,
                              hipStream_t stream) {
    const float* coord = (const float*)d_in[0];   // [4096, 3] fp32
    const float* cell  = (const float*)d_in[1];   // [3, 3] fp32, L*I
    float* out = (float*)d_out;                    // 4096^2 + 4096^2*3 fp32

    hipLaunchKernelGGL(cellnl_kernel, dim3(N_ATOMS), dim3(TPB), 0, stream,
                       coord, cell, out);
}